// Round 1
// baseline (356.962 us; speedup 1.0000x reference)
//
#include <hip/hip_runtime.h>
#include <stdint.h>

// One wave (64 lanes) per batch row. B=16384 rows, T=4096 int32 each.
//
// v2 redesign vs. ballot version:
//  - Global reads: 16 x dwordx4 per row (1KB per wave-instr), ALL issued up
//    front -> 16KB outstanding per wave, sequential DRAM bursts (old version:
//    64 x dword = 256B requests with vmcnt(0) drain every 4KB -> ~757 GB/s).
//  - Transpose via per-wave XOR-swizzled LDS (no __syncthreads needed; a wave
//    only touches its own 8KB buffer). Write quad = (lane&7)^((4c+lane>>4)&7),
//    read quad = j^((i>>1)&7): both 8 lanes/quad even spread -> conflict-free.
//  - Each lane builds a 32-bit mask of its own contiguous 32-element segment
//    locally: zero ballots, zero serial cndmask capture chain.
//  - Row processed as two 2048-element halves (8KB LDS each) so the block
//    needs only 32KB LDS -> 4 blocks/CU = 16 waves/CU.

#define NROWS 16384
#define TLEN  4096

__device__ __forceinline__ int swz(int idx) { return idx ^ ((idx >> 4) & 15); }

// Leaf summary of a 32-element mask + 6-step shuffle-tree merge across the
// wave. On return, lane 0 holds the run-length monoid summary of the 2048
// elements covered by this wave for this half: {ch, cl, lead, trail}.
//   ch   = # completed interior runs >= 4
//   cl   = # completed interior runs >= 7
//   lead = length of run touching segment start (== len -> fully yawning)
//   trail= length of run touching segment end
__device__ __forceinline__ void leaf_tree(uint32_t m,
                                          int& ch, int& cl, int& lead, int& trail)
{
    bool full  = (m == 0xFFFFFFFFu);
    uint32_t nm = ~m;
    lead  = full ? 32 : __builtin_ctz(nm);   // run touching segment start
    trail = full ? 32 : __builtin_clz(nm);   // run touching segment end

    int lc = full ? 0 : lead;                // keep shift counts < 32
    int tc = full ? 0 : trail;
    uint32_t mi = full ? 0u : m;             // interior mask: boundary runs cleared
    mi = (mi >> lc) << lc;
    mi = (mi << tc) >> tc;

    uint32_t w = mi & (mi >> 1);             // w bit i <=> m[i..i+3] all set
    w &= (w >> 2);
    ch = __builtin_popcount(w & ~(w << 1));  // # runs >= 4 (run-starts)
    uint32_t w7 = w & (w >> 3);              // w7 bit i <=> m[i..i+6] all set
    cl = __builtin_popcount(w7 & ~(w7 << 1));

    #pragma unroll
    for (int off = 1, len = 32; off < 64; off <<= 1, len <<= 1) {
        int bch    = __shfl_down(ch,    (unsigned)off, 64);
        int bcl    = __shfl_down(cl,    (unsigned)off, 64);
        int blead  = __shfl_down(lead,  (unsigned)off, 64);
        int btrail = __shfl_down(trail, (unsigned)off, 64);

        bool afull = (lead  == len);
        bool bfull = (blead == len);
        int junction = trail + blead;        // run spanning the seam
        bool interior = (!afull) && (!bfull);
        ch += bch + ((interior && junction >= 4) ? 1 : 0);
        cl += bcl + ((interior && junction >= 7) ? 1 : 0);
        lead  = afull ? (len + blead) : lead;
        trail = bfull ? (len + trail) : btrail;
    }
}

// Each lane reads its contiguous 32-element segment (8 swizzled b128 reads)
// and packs the yawning bits, LSB = earliest element.
__device__ __forceinline__ uint32_t build_mask(const uint4* buf, int lane)
{
    uint32_t m = 0;
    #pragma unroll
    for (int j = 0; j < 8; ++j) {
        uint4 q = buf[swz(lane * 8 + j)];
        uint32_t nib = (q.x == 2 ? 1u : 0u) | (q.y == 2 ? 2u : 0u)
                     | (q.z == 2 ? 4u : 0u) | (q.w == 2 ? 8u : 0u);
        m |= nib << (4 * j);
    }
    return m;
}

__global__ __launch_bounds__(256, 4) void yawn_adjust_kernel(
    const float* __restrict__ drows,
    const int* __restrict__ gest,
    float* __restrict__ out)
{
    __shared__ uint4 lds[4][512];            // 8KB per wave, 32KB per block
    const int lane = threadIdx.x & 63;
    const int wid  = (int)(threadIdx.x >> 6);
    const int row  = blockIdx.x * 4 + wid;   // grid is exact: no bounds check
    uint4* buf = lds[wid];

    const uint4* g4 = (const uint4*)gest + (size_t)row * (TLEN / 4);

    // ---- Issue ALL global loads up front: 16KB outstanding per wave,
    // coalesced 1KB per instruction.
    uint4 a[8], b[8];
    #pragma unroll
    for (int c = 0; c < 8; ++c) a[c] = g4[c * 64 + lane];
    #pragma unroll
    for (int c = 0; c < 8; ++c) b[c] = g4[512 + c * 64 + lane];

    // ---- Half 0: stage -> per-lane mask -> summary (waits only on a[]).
    #pragma unroll
    for (int c = 0; c < 8; ++c) buf[swz(c * 64 + lane)] = a[c];
    uint32_t m0 = build_mask(buf, lane);
    int ch0, cl0, lead0, trail0;
    leaf_tree(m0, ch0, cl0, lead0, trail0);

    // ---- Half 1 (b[] loads have been in flight the whole time).
    #pragma unroll
    for (int c = 0; c < 8; ++c) buf[swz(c * 64 + lane)] = b[c];
    uint32_t m1 = build_mask(buf, lane);
    int ch1, cl1, lead1, trail1;
    leaf_tree(m1, ch1, cl1, lead1, trail1);

    // ---- Combine the two 2048-element halves (valid on lane 0).
    bool afull = (lead0 == 2048);
    bool bfull = (lead1 == 2048);
    int junction = trail0 + lead1;
    bool interior = (!afull) && (!bfull);
    int ch = ch0 + ch1 + ((interior && junction >= 4) ? 1 : 0);
    int cl = cl0 + cl1 + ((interior && junction >= 7) ? 1 : 0);
    int lead  = afull ? (2048 + lead1)  : lead0;
    int trail = bfull ? (2048 + trail0) : trail1;

    // ---- Finalize + epilogue (lane 0 only).
    if (lane == 0) {
        int hc, lc;
        if (lead == TLEN) {                  // entire row is one run
            hc = 1; lc = 1;
        } else {
            hc = ch + (lead >= 4 ? 1 : 0) + (trail >= 4 ? 1 : 0);
            lc = cl + (lead >= 7 ? 1 : 0) + (trail >= 7 ? 1 : 0);
        }
        float hadj = (hc >= 2) ? 0.18f * expf(-0.5f * (float)(hc - 2)) : 0.0f;
        float ladj = (lc >= 3) ? 0.05f * expf(-0.5f * (float)(lc - 3)) : 0.0f;
        float tot  = fminf(hadj + ladj, 0.35f);
        float r    = drows[row] + tot;
        out[row]   = fminf(fmaxf(r, 0.0f), 1.0f);
    }
}

extern "C" void kernel_launch(void* const* d_in, const int* in_sizes, int n_in,
                              void* d_out, int out_size, void* d_ws, size_t ws_size,
                              hipStream_t stream) {
    (void)in_sizes; (void)n_in; (void)d_ws; (void)ws_size; (void)out_size;
    const float* drows = (const float*)d_in[0];
    const int*   gest  = (const int*)d_in[1];
    float*       out   = (float*)d_out;
    dim3 grid(NROWS / 4);   // 4 waves per 256-thread block, one row per wave
    yawn_adjust_kernel<<<grid, 256, 0, stream>>>(drows, gest, out);
}